// Round 1
// 3693.870 us; speedup vs baseline: 2.2632x; 2.2632x over previous
//
#include <hip/hip_runtime.h>
#include <cstdint>
#include <cstddef>

#define BD 32
#define TD 4096
#define ID 256
#define OD 256

// f32 constants, computed in f64 and rounded (matches np.exp on f32 within <=1 ulp)
#define A_DEND 0.90483741803595957f   // exp(-1/10)
#define A_SYN  0.81873075307798182f   // exp(-1/5)
#define A_MEM  0.95122942450071402f   // exp(-1/20)
#define TWO_PI_F 6.28318530717958647692f
#define BASE_DTH 62.8318530717958647692f  // 2*pi*10
#define INV256 0.00390625f

#define DOT4(acc, xv, wv)               \
  acc = fmaf((xv).x, (wv).x, acc);      \
  acc = fmaf((xv).y, (wv).y, acc);      \
  acc = fmaf((xv).z, (wv).z, acc);      \
  acc = fmaf((xv).w, (wv).w, acc);

// ---------------------------------------------------------------------------
// Phase A: weights-in-LDS persistent blocks.
// Block = 512 threads, owns 16 o-columns; stages all 7x16 weight rows (K=256)
// into LDS ONCE (112 rows x 260-padded stride = 114 KB), then loops 32 m-tiles
// of 64 rows, streaming x through a double-buffered 64x64 chunk (68-padded
// rows; reg-staged issue-early/write-late, one barrier per chunk).
// Inner loop: 9 ds_read_b128 + 56 v_fmac per thread per k4-step, immediate
// offsets only, NO global loads.  Same k-order/fma chain as the previous
// passing kernel -> bit-identical sums.
// ---------------------------------------------------------------------------

#define WSTR 260              // weight row stride (floats): bank step 4 -> 2-way (free)
#define XROWSTR 68            // x row stride (floats): rows {0,2,4,6} land on banks {0,8,16,24}
#define XCHF (64 * XROWSTR)   // 4352 floats per chunk buffer

__global__ __launch_bounds__(512, 1)
void proj_kernel(const float* __restrict__ x,
                 const float* __restrict__ Ws,
                 const float* __restrict__ Wb,
                 const float* __restrict__ Wa,
                 float* __restrict__ soma_ws,
                 float* __restrict__ u_ws) {
  #pragma clang fp contract(off)
  __shared__ float wl[112 * WSTR];   // 116,480 B
  __shared__ float xcf[2 * XCHF];    //  34,816 B   (total 151,296 <= 160 KiB)

  const int tid = threadIdx.x;
  // XCD-chunked bijective swizzle over the 16x64 grid: the 16 o-blocks that
  // share an x m-range land on one XCD's L2.
  const int lin = (int)blockIdx.x + ((int)blockIdx.y << 4);   // 0..1023
  const int swz = ((lin & 7) << 7) + (lin >> 3);
  const int o0  = (swz & 15) << 4;
  const int by  = swz >> 4;                                   // 0..63

  // ---- stage weights: rows [0..15]=Ws, [16..79]=Wb(nb=0..3), [80..111]=Wa ----
  for (int rep = 0; rep < 14; ++rep) {
    int f = (rep << 9) + tid;          // float4 index 0..7167
    int r = f >> 6;                    // 0..111
    int c = (f & 63) << 2;             // float col 0..252
    const float* src;
    if (r < 16) {
      src = Ws + (((size_t)(o0 + r)) << 8);
    } else if (r < 80) {
      src = Wb + (((size_t)((((r - 16) >> 4) << 8) + o0 + (r & 15))) << 8);
    } else {
      src = Wa + (((size_t)((((r - 80) >> 4) << 8) + o0 + (r & 15))) << 8);
    }
    *(float4*)(&wl[r * WSTR + c]) = *(const float4*)(src + c);
  }

  const int oo = tid & 15;
  const int mr = (tid >> 4) << 1;      // 0,2,...,62: this thread's two m-rows
  const float* w0p = wl + (  0 + oo) * WSTR;
  const float* w1p = wl + ( 16 + oo) * WSTR;
  const float* w2p = wl + ( 32 + oo) * WSTR;
  const float* w3p = wl + ( 48 + oo) * WSTR;
  const float* w4p = wl + ( 64 + oo) * WSTR;
  const float* w5p = wl + ( 80 + oo) * WSTR;
  const float* w6p = wl + ( 96 + oo) * WSTR;

  // x staging map: chunk = 1024 float4; this thread moves f0=tid and f1=tid+512
  const int f0 = tid, f1 = tid + 512;
  const int sr0 = f0 >> 4, sc0 = (f0 & 15) << 2;
  const int sr1 = f1 >> 4, sc1 = (f1 & 15) << 2;
  const int d0 = sr0 * XROWSTR + sc0;
  const int d1 = sr1 * XROWSTR + sc1;

  const size_t trow0 = ((size_t)by) << 11;     // first m-row of this block (by*2048)

  // initial stage: (mt=0, kc=0) -> buf0
  {
    *(float4*)(&xcf[d0]) = *(const float4*)(x + (trow0 + sr0) * ID + sc0);
    *(float4*)(&xcf[d1]) = *(const float4*)(x + (trow0 + sr1) * ID + sc1);
  }
  __syncthreads();

  for (int mt = 0; mt < 32; ++mt) {
    const size_t row0 = trow0 + ((size_t)mt << 6);
    float acS[2]  = {0.f, 0.f}, acB0[2] = {0.f, 0.f}, acB1[2] = {0.f, 0.f},
          acB2[2] = {0.f, 0.f}, acB3[2] = {0.f, 0.f}, acA0[2] = {0.f, 0.f},
          acA1[2] = {0.f, 0.f};
    #pragma unroll
    for (int kc = 0; kc < 4; ++kc) {
      // T14 issue-early: load next chunk to regs before compute
      float4 pa = {0.f, 0.f, 0.f, 0.f}, pb = {0.f, 0.f, 0.f, 0.f};
      const bool hn = !(kc == 3 && mt == 31);
      if (hn) {
        const size_t nrow = (kc < 3) ? row0 : (row0 + 64);
        const int nk = (kc < 3) ? ((kc + 1) << 6) : 0;
        pa = *(const float4*)(x + (nrow + sr0) * ID + nk + sc0);
        pb = *(const float4*)(x + (nrow + sr1) * ID + nk + sc1);
      }
      // compute on buf = kc&1 (static under unroll -> immediate LDS offsets)
      const float* xA = xcf + ((kc & 1) ? XCHF : 0) + mr * XROWSTR;
      const float* xB = xA + XROWSTR;
      #pragma unroll 4
      for (int kk = 0; kk < 64; kk += 4) {
        float4 xv0 = *(const float4*)(xA + kk);
        float4 xv1 = *(const float4*)(xB + kk);
        float4 vs  = *(const float4*)(w0p + (kc << 6) + kk);
        float4 vb0 = *(const float4*)(w1p + (kc << 6) + kk);
        float4 vb1 = *(const float4*)(w2p + (kc << 6) + kk);
        float4 vb2 = *(const float4*)(w3p + (kc << 6) + kk);
        float4 vb3 = *(const float4*)(w4p + (kc << 6) + kk);
        float4 va0 = *(const float4*)(w5p + (kc << 6) + kk);
        float4 va1 = *(const float4*)(w6p + (kc << 6) + kk);
        DOT4(acS[0], xv0, vs)   DOT4(acS[1], xv1, vs)
        DOT4(acB0[0], xv0, vb0) DOT4(acB0[1], xv1, vb0)
        DOT4(acB1[0], xv0, vb1) DOT4(acB1[1], xv1, vb1)
        DOT4(acB2[0], xv0, vb2) DOT4(acB2[1], xv1, vb2)
        DOT4(acB3[0], xv0, vb3) DOT4(acB3[1], xv1, vb3)
        DOT4(acA0[0], xv0, va0) DOT4(acA0[1], xv1, va0)
        DOT4(acA1[0], xv0, va1) DOT4(acA1[1], xv1, va1)
      }
      // write-late into the other buffer, then one barrier per chunk
      if (hn) {
        float* dst = xcf + (((kc & 1) ^ 1) ? XCHF : 0);
        *(float4*)(dst + d0) = pa;
        *(float4*)(dst + d1) = pb;
      }
      __syncthreads();
    }
    // epilogue: identical expressions/roundings to the previous passing kernel
    const size_t mb = (row0 + mr) * OD + (o0 + oo);
    #pragma unroll
    for (int j = 0; j < 2; ++j) {
      float bm = ((fmaxf(acB0[j], 0.f) + fmaxf(acB1[j], 0.f)) +
                  (fmaxf(acB2[j], 0.f) + fmaxf(acB3[j], 0.f))) * 0.25f;
      float am = (fmaxf(acA0[j], 0.f) + fmaxf(acA1[j], 0.f)) * 0.5f;
      soma_ws[mb + (size_t)j * OD] = acS[j];
      u_ws[mb + (size_t)j * OD]    = bm + am;
    }
  }
}

// ---------------------------------------------------------------------------
// Phase B: sequential LIF + Kuramoto. 32 blocks x 1 wave; lane owns o=4l..4l+3.
// Changes vs previous: (1) spike = (v>0) directly -- bit-identical to
// sg + (hh - sg) in f32 (h=0: a+fl(-a)=0 exact; h=1: v>0 => sg>=0.5 =>
// 1-sg Sterbenz-exact => sum == 1.0), drops expf+rcp from the hot loop.
// (2) prefetch depth 2 chunks (A/B ring, statically indexed via 2x unroll)
// so ~8 steps of compute cover the ~900-cycle HBM latency.
// ---------------------------------------------------------------------------

#define DPP_ADD(v, ctrl, rm, bm, bc)                                          \
  v += __builtin_bit_cast(float, __builtin_amdgcn_update_dpp(                 \
           0, __builtin_bit_cast(int, v), ctrl, rm, bm, bc));

__device__ __forceinline__ float wave_sum64(float v) {
  DPP_ADD(v, 0x111, 0xf, 0xf, true)    // row_shr:1
  DPP_ADD(v, 0x112, 0xf, 0xf, true)    // row_shr:2
  DPP_ADD(v, 0x114, 0xf, 0xf, true)    // row_shr:4
  DPP_ADD(v, 0x118, 0xf, 0xf, true)    // row_shr:8
  DPP_ADD(v, 0x142, 0xa, 0xf, false)   // row_bcast:15 -> rows 1,3
  DPP_ADD(v, 0x143, 0xc, 0xf, false)   // row_bcast:31 -> rows 2,3
  return __builtin_bit_cast(float, __builtin_amdgcn_readlane(__builtin_bit_cast(int, v), 63));
}

#define PROCESS4(TBASE)                                                       \
  _Pragma("unroll")                                                           \
  for (int i = 0; i < 4; ++i) {                                               \
    const int t = (TBASE) + i;                                                \
    const float* sv = &cs[i].x;                                               \
    const float* uv = &cu[i].x;                                               \
    float spk[4], cc[4], ss[4];                                               \
    _Pragma("unroll")                                                         \
    for (int j = 0; j < 4; ++j) {                                             \
      float t1 = A_DEND * dend[j];                                            \
      float t2 = bD * uv[j];                                                  \
      dend[j] = t1 + t2;                                                      \
      float drive = sv[j] + 0.5f * dend[j];                                   \
      syn[j] = (A_SYN * syn[j]) + drive;                                      \
      mem[j] = (A_MEM * mem[j]) + syn[j];                                     \
      float v = mem[j] - 1.0f;                                                \
      float sp = (v > 0.0f) ? 1.0f : 0.0f;                                    \
      mem[j] = mem[j] - sp;                                                   \
      spk[j] = sp;                                                            \
      cc[j] = __cosf(th[j]);                                                  \
      ss[j] = __sinf(th[j]);                                                  \
    }                                                                         \
    float csum = (cc[0] + cc[1]) + (cc[2] + cc[3]);                           \
    float ssum = (ss[0] + ss[1]) + (ss[2] + ss[3]);                           \
    float cS = wave_sum64(csum);                                              \
    float sS = wave_sum64(ssum);                                              \
    _Pragma("unroll")                                                         \
    for (int j = 0; j < 4; ++j) {                                             \
      float coup = (sS * cc[j] - cS * ss[j]) * INV256;                        \
      float dth = (BASE_DTH + coup) + spk[j];                                 \
      th[j] = th[j] + 0.001f * dth;                                           \
      th[j] = (th[j] >= TWO_PI_F) ? (th[j] - TWO_PI_F) : th[j];               \
    }                                                                         \
    float4 so = {spk[0], spk[1], spk[2], spk[3]};                             \
    float4 po = {th[0], th[1], th[2], th[3]};                                 \
    float4 mo = {mem[0], mem[1], mem[2], mem[3]};                             \
    Os[(size_t)t * 64] = so;                                                  \
    Op[(size_t)t * 64] = po;                                                  \
    Om[(size_t)t * 64] = mo;                                                  \
  }

__global__ __launch_bounds__(64, 1)
void dyn_kernel(const float* __restrict__ soma_ws,
                const float* __restrict__ u_ws,
                float* __restrict__ out) {
  // Match numpy's per-op rounding: no mul+add fusion except explicit fmaf.
  #pragma clang fp contract(off)
  const int b = blockIdx.x;
  const int l = threadIdx.x;

  const size_t base4 = ((size_t)b << 18) + l;        // float4 units
  const float4* S = (const float4*)soma_ws + base4;
  const float4* U = (const float4*)u_ws + base4;
  float4* Os = (float4*)out + base4;                 // spikes
  float4* Op = Os + ((size_t)1 << 23);               // phases
  float4* Om = Op + ((size_t)1 << 23);               // membrane

  float dend[4] = {0.f, 0.f, 0.f, 0.f};
  float syn[4]  = {0.f, 0.f, 0.f, 0.f};
  float mem[4]  = {0.f, 0.f, 0.f, 0.f};
  float th[4]   = {0.f, 0.f, 0.f, 0.f};

  const float bD = 1.0f - A_DEND;   // exact (Sterbenz)

  float4 As[4], Au[4], Bs[4], Bu[4];
  #pragma unroll
  for (int i = 0; i < 4; ++i) { As[i] = S[(size_t)i * 64];       Au[i] = U[(size_t)i * 64]; }
  #pragma unroll
  for (int i = 0; i < 4; ++i) { Bs[i] = S[(size_t)(4 + i) * 64]; Bu[i] = U[(size_t)(4 + i) * 64]; }

  for (int t8 = 0; t8 < TD / 8; ++t8) {
    float4 cs[4], cu[4];
    #pragma unroll
    for (int i = 0; i < 4; ++i) { cs[i] = As[i]; cu[i] = Au[i]; }
    if (t8 < TD / 8 - 1) {         // refill A with chunk 2*t8+2
      #pragma unroll
      for (int i = 0; i < 4; ++i) {
        As[i] = S[(size_t)((t8 << 3) + 8 + i) * 64];
        Au[i] = U[(size_t)((t8 << 3) + 8 + i) * 64];
      }
    }
    PROCESS4((t8 << 3));
    #pragma unroll
    for (int i = 0; i < 4; ++i) { cs[i] = Bs[i]; cu[i] = Bu[i]; }
    if (t8 < TD / 8 - 1) {         // refill B with chunk 2*t8+3
      #pragma unroll
      for (int i = 0; i < 4; ++i) {
        Bs[i] = S[(size_t)((t8 << 3) + 12 + i) * 64];
        Bu[i] = U[(size_t)((t8 << 3) + 12 + i) * 64];
      }
    }
    PROCESS4((t8 << 3) + 4);
  }
}

// ---------------------------------------------------------------------------

extern "C" void kernel_launch(void* const* d_in, const int* in_sizes, int n_in,
                              void* d_out, int out_size, void* d_ws, size_t ws_size,
                              hipStream_t stream) {
  const float* x  = (const float*)d_in[0];
  const float* Ws = (const float*)d_in[1];
  const float* Wb = (const float*)d_in[2];
  const float* Wa = (const float*)d_in[3];

  float* soma_ws = (float*)d_ws;
  float* u_ws    = soma_ws + (size_t)BD * TD * OD;   // +33554432 floats
  float* out     = (float*)d_out;

  dim3 gA(16, 64, 1);   // 16 o-groups x 64 m-ranges, persistent over 32 m-tiles each
  proj_kernel<<<gA, 512, 0, stream>>>(x, Ws, Wb, Wa, soma_ws, u_ws);
  dyn_kernel<<<BD, 64, 0, stream>>>(soma_ws, u_ws, out);
}